// Round 1
// baseline (671.032 us; speedup 1.0000x reference)
//
#include <hip/hip_runtime.h>

#define FH 64
#define FW 64
#define NWF 33
#define NBIN (FH*NWF)      // 2112
#define NIMG 4096          // 4 * 32 * 32
#define PI2 6.283185307179586f

__device__ __forceinline__ void cmadd(float2& a, float2 w, float2 x) {
    a.x = fmaf(w.x, x.x, a.x); a.x = fmaf(-w.y, x.y, a.x);
    a.y = fmaf(w.x, x.y, a.y); a.y = fmaf(w.y, x.x, a.y);
}
__device__ __forceinline__ void cmsub(float2& a, float2 w, float2 x) {
    a.x = fmaf(-w.x, x.x, a.x); a.x = fmaf(w.y, x.y, a.x);
    a.y = fmaf(-w.x, x.y, a.y); a.y = fmaf(-w.y, x.x, a.y);
}

// ---------------- forward rfft2: one block per image ----------------
__global__ __launch_bounds__(256) void fft_fwd_kernel(const float* __restrict__ x,
                                                      float2* __restrict__ Xs)
{
    const int img = blockIdx.x;        // p*1024 + b*32 + i
    const int p  = img >> 10;
    const int b  = (img >> 5) & 31;
    const int ci = img & 31;
    const float* __restrict__ src = x + ((size_t)b*128 + (size_t)p*32 + ci) * (FH*FW);

    __shared__ float  s_img[FH*FW];
    __shared__ float2 s_row[FH][NWF];
    __shared__ float2 s_tw[64];        // e^{-2pi i n/64}

    const int tid = threadIdx.x;
    if (tid < 64) {
        float ang = -PI2 * (float)tid / 64.0f;
        s_tw[tid] = make_float2(cosf(ang), sinf(ang));
    }
    for (int t = tid; t < FH*FW; t += 256) s_img[t] = src[t];
    __syncthreads();

    // row rFFT along W: output (h, k) for k=0..32
    for (int t = tid; t < NBIN; t += 256) {
        const int h = t / NWF;
        const int k = t - h*NWF;
        const float* row = &s_img[h*FW];
        float re = 0.f, im = 0.f;
        #pragma unroll 8
        for (int w = 0; w < FW; ++w) {
            float v = row[w];
            float2 tw = s_tw[(k*w) & 63];
            re = fmaf(v, tw.x, re);
            im = fmaf(v, tw.y, im);
        }
        s_row[h][k] = make_float2(re, im);
    }
    __syncthreads();

    // column complex FFT along H, write coalesced: Xs[img][bin], bin = hk*33 + k
    float2* __restrict__ dst = Xs + (size_t)img * NBIN;
    for (int t = tid; t < NBIN; t += 256) {
        const int hk = t / NWF;
        const int k  = t - hk*NWF;
        float re = 0.f, im = 0.f;
        #pragma unroll 8
        for (int h = 0; h < FH; ++h) {
            float2 v  = s_row[h][k];
            float2 tw = s_tw[(hk*h) & 63];
            re = fmaf(v.x, tw.x, re); re = fmaf(-v.y, tw.y, re);
            im = fmaf(v.x, tw.y, im); im = fmaf(v.y, tw.x, im);
        }
        dst[t] = make_float2(re, im);
    }
}

// ---------------- per-bin quaternion contraction: one block per bin ----------------
__global__ __launch_bounds__(256) void contract_kernel(
    const float* __restrict__ krw, const float* __restrict__ krx,
    const float* __restrict__ kry, const float* __restrict__ krz,
    const float* __restrict__ kiw, const float* __restrict__ kix,
    const float* __restrict__ kiy, const float* __restrict__ kiz,
    const float2* __restrict__ Xs, float2* __restrict__ P)
{
    const int bin = blockIdx.x;
    __shared__ float2 sW[4][32*32];    // [p][i*32+o]
    __shared__ float2 sX[4][32*32];    // [q][b*32+i]
    const int tid = threadIdx.x;

    const float* kr[4] = {krw, krx, kry, krz};
    const float* ki[4] = {kiw, kix, kiy, kiz};
    #pragma unroll
    for (int p = 0; p < 4; ++p) {
        const float* __restrict__ rr = kr[p];
        const float* __restrict__ ii = ki[p];
        for (int t = tid; t < 1024; t += 256) {
            size_t idx = (size_t)t * NBIN + bin;   // weight layout [i][o][h][wf]
            sW[p][t] = make_float2(rr[idx], ii[idx]);
        }
    }
    for (int t = tid; t < 4096; t += 256) {        // t = q*1024 + b*32 + i = img
        (&sX[0][0])[t] = Xs[(size_t)t * NBIN + bin];
    }
    __syncthreads();

    const int b  = tid >> 3;
    const int o0 = (tid & 7) << 2;
    float2 acc[4][4];
    #pragma unroll
    for (int c = 0; c < 4; ++c)
        #pragma unroll
        for (int oo = 0; oo < 4; ++oo) acc[c][oo] = make_float2(0.f, 0.f);

    for (int i = 0; i < 32; ++i) {
        float2 xw = sX[0][b*32+i], xx = sX[1][b*32+i];
        float2 xy = sX[2][b*32+i], xz = sX[3][b*32+i];
        #pragma unroll
        for (int oo = 0; oo < 4; ++oo) {
            const int o = o0 + oo;
            float2 ww = sW[0][i*32+o], wx = sW[1][i*32+o];
            float2 wy = sW[2][i*32+o], wz = sW[3][i*32+o];
            // Hamilton product combination (per reference einsum + signs)
            cmadd(acc[0][oo], ww, xw); cmsub(acc[0][oo], wx, xx); cmsub(acc[0][oo], wy, xy); cmsub(acc[0][oo], wz, xz);
            cmadd(acc[1][oo], ww, xx); cmadd(acc[1][oo], wx, xw); cmadd(acc[1][oo], wy, xz); cmsub(acc[1][oo], wz, xy);
            cmadd(acc[2][oo], ww, xy); cmsub(acc[2][oo], wx, xz); cmadd(acc[2][oo], wy, xw); cmadd(acc[2][oo], wz, xx);
            cmadd(acc[3][oo], ww, xz); cmadd(acc[3][oo], wx, xy); cmsub(acc[3][oo], wy, xx); cmadd(acc[3][oo], wz, xw);
        }
    }
    // P layout: [bin][p][b][o], coalesced write
    float2* __restrict__ dst = P + (size_t)bin * 4096;
    #pragma unroll
    for (int p = 0; p < 4; ++p)
        #pragma unroll
        for (int oo = 0; oo < 4; ++oo)
            dst[p*1024 + b*32 + o0 + oo] = acc[p][oo];
}

// ---------------- inverse rfft2: one block per output image ----------------
__global__ __launch_bounds__(256) void fft_inv_kernel(const float2* __restrict__ P,
                                                      float* __restrict__ out)
{
    const int img = blockIdx.x;        // p*1024 + b*32 + o
    const int p  = img >> 10;
    const int b  = (img >> 5) & 31;
    const int oc = img & 31;

    __shared__ float2 sS[FH][NWF];
    __shared__ float2 sT[FH][NWF];
    __shared__ float2 s_tw[64];        // e^{+2pi i n/64}

    const int tid = threadIdx.x;
    if (tid < 64) {
        float ang = PI2 * (float)tid / 64.0f;
        s_tw[tid] = make_float2(cosf(ang), sinf(ang));
    }
    for (int t = tid; t < NBIN; t += 256) {
        (&sS[0][0])[t] = P[(size_t)t * NIMG + img];   // gather from [bin][pbo]
    }
    __syncthreads();

    // inverse complex FFT along H (scale deferred)
    for (int t = tid; t < NBIN; t += 256) {
        const int n = t / NWF;
        const int k = t - n*NWF;
        float re = 0.f, im = 0.f;
        #pragma unroll 8
        for (int m = 0; m < FH; ++m) {
            float2 v  = sS[m][k];
            float2 tw = s_tw[(m*n) & 63];
            re = fmaf(v.x, tw.x, re); re = fmaf(-v.y, tw.y, re);
            im = fmaf(v.x, tw.y, im); im = fmaf(v.y, tw.x, im);
        }
        sT[n][k] = make_float2(re, im);
    }
    __syncthreads();

    // inverse rFFT along W (pocketfft convention: imag of DC/Nyquist ignored)
    const float scale = 1.0f / 4096.0f;
    float* __restrict__ dst = out + ((size_t)b*128 + (size_t)p*32 + oc) * (FH*FW);
    for (int t = tid; t < FH*FW; t += 256) {
        const int n = t >> 6;
        const int w = t & 63;
        float acc = 0.f;
        #pragma unroll 8
        for (int k = 1; k < 32; ++k) {
            float2 v  = sT[n][k];
            float2 tw = s_tw[(k*w) & 63];
            acc = fmaf(v.x, tw.x, acc);
            acc = fmaf(-v.y, tw.y, acc);
        }
        float r = sT[n][0].x + ((w & 1) ? -sT[n][32].x : sT[n][32].x) + 2.f*acc;
        dst[t] = r * scale;
    }
}

extern "C" void kernel_launch(void* const* d_in, const int* in_sizes, int n_in,
                              void* d_out, int out_size, void* d_ws, size_t ws_size,
                              hipStream_t stream)
{
    const float* x   = (const float*)d_in[0];
    const float* krw = (const float*)d_in[1];
    const float* krx = (const float*)d_in[2];
    const float* kry = (const float*)d_in[3];
    const float* krz = (const float*)d_in[4];
    const float* kiw = (const float*)d_in[5];
    const float* kix = (const float*)d_in[6];
    const float* kiy = (const float*)d_in[7];
    const float* kiz = (const float*)d_in[8];

    float2* Xs = (float2*)d_ws;                       // [img=4096][bin=2112]
    float2* P  = Xs + (size_t)NIMG * NBIN;            // [bin=2112][p*b*o=4096]
    float*  out = (float*)d_out;

    fft_fwd_kernel<<<dim3(NIMG), dim3(256), 0, stream>>>(x, Xs);
    contract_kernel<<<dim3(NBIN), dim3(256), 0, stream>>>(krw, krx, kry, krz,
                                                          kiw, kix, kiy, kiz, Xs, P);
    fft_inv_kernel<<<dim3(NIMG), dim3(256), 0, stream>>>(P, out);
}

// Round 2
// 332.988 us; speedup vs baseline: 2.0152x; 2.0152x over previous
//
#include <hip/hip_runtime.h>

#define FH 64
#define FW 64
#define NWF 33
#define NBIN (FH*NWF)      // 2112
#define NIMG 4096          // 4 * 32 * 32
#define PI2 6.283185307179586f

__device__ __forceinline__ int brev6(int v) { return (int)(__brev((unsigned)v) >> 26); }

__device__ __forceinline__ void cmadd(float2& a, float2 w, float2 x) {
    a.x = fmaf(w.x, x.x, a.x); a.x = fmaf(-w.y, x.y, a.x);
    a.y = fmaf(w.x, x.y, a.y); a.y = fmaf(w.y, x.x, a.y);
}
__device__ __forceinline__ void cmsub(float2& a, float2 w, float2 x) {
    a.x = fmaf(-w.x, x.x, a.x); a.x = fmaf(w.y, x.y, a.x);
    a.y = fmaf(-w.x, x.y, a.y); a.y = fmaf(-w.y, x.x, a.y);
}

// One radix-2 DIF stage butterfly. Element at flat LDS index addr(p).
// After 6 stages, output position p holds bin brev6(p).
#define BFLY(ARR, P0, P1, JJ, S)                                        \
    {                                                                   \
        float2 u = ARR[P0], v = ARR[P1];                                \
        float2 tw = s_tw[((JJ) << (S)) & 63];                           \
        float2 d = make_float2(u.x - v.x, u.y - v.y);                   \
        ARR[P0] = make_float2(u.x + v.x, u.y + v.y);                    \
        ARR[P1] = make_float2(d.x*tw.x - d.y*tw.y, d.x*tw.y + d.y*tw.x);\
    }

// ---------------- forward rfft2: one block per image ----------------
__global__ __launch_bounds__(256) void fft_fwd_kernel(const float* __restrict__ x,
                                                      float2* __restrict__ Xs)
{
    const int img = blockIdx.x;        // p*1024 + b*32 + i
    const int p  = img >> 10;
    const int b  = (img >> 5) & 31;
    const int ci = img & 31;
    const float* __restrict__ src = x + ((size_t)b*128 + (size_t)p*32 + ci) * (FH*FW);

    __shared__ float2 zrow[32*64];     // packed row pairs: re=row 2r, im=row 2r+1
    __shared__ float2 scol[64*NWF];    // row spectra [h][k]
    __shared__ float2 s_tw[64];        // e^{-2pi i n/64}

    const int tid = threadIdx.x;
    if (tid < 64) {
        float ang = -PI2 * (float)tid / 64.0f;
        s_tw[tid] = make_float2(cosf(ang), sinf(ang));
    }
    // load + pack two real rows into one complex row
    for (int t = tid; t < 1024; t += 256) {
        float4 v = ((const float4*)src)[t];
        int flat = t << 2, row = flat >> 6, w = flat & 63;
        int r = row >> 1, comp = row & 1;
        float* base = (float*)&zrow[r*64 + w];
        base[0+comp] = v.x; base[2+comp] = v.y; base[4+comp] = v.z; base[6+comp] = v.w;
    }
    __syncthreads();

    // 6 DIF stages over each of 32 packed rows (length 64, contiguous)
    for (int s = 0; s < 6; ++s) {
        const int half = 32 >> s;
        for (int t = tid; t < 1024; t += 256) {
            int j = t & 31, r = t >> 5;
            int jj = j & (half - 1);
            int p0 = ((j >> (5 - s)) << (6 - s)) + jj;
            float2* a = &zrow[r*64];
            BFLY(a, p0, p0 + half, jj, s);
        }
        __syncthreads();
    }

    // unpack packed spectra: A = spectrum of row 2r, B = row 2r+1
    for (int t = tid; t < 1056; t += 256) {
        int r = t / 33, k = t - r*33;
        float2 Zp = zrow[r*64 + brev6(k)];
        float2 Zq = zrow[r*64 + brev6((64 - k) & 63)];   // Z[64-k]
        float2 A = make_float2(0.5f*(Zp.x + Zq.x), 0.5f*(Zp.y - Zq.y));
        float2 B = make_float2(0.5f*(Zp.y + Zq.y), -0.5f*(Zp.x - Zq.x));
        scol[(2*r)*NWF + k]   = A;
        scol[(2*r+1)*NWF + k] = B;
    }
    __syncthreads();

    // 6 DIF stages along h for each k (element stride NWF)
    for (int s = 0; s < 6; ++s) {
        const int half = 32 >> s;
        for (int t = tid; t < 1056; t += 256) {
            int j = t / 33, k = t - j*33;
            int jj = j & (half - 1);
            int p0 = ((j >> (5 - s)) << (6 - s)) + jj;
            BFLY(scol, p0*NWF + k, (p0 + half)*NWF + k, jj, s);
        }
        __syncthreads();
    }

    // write out, undoing bit-reversal on h: Xs[img][hk*33+k]
    float2* __restrict__ dst = Xs + (size_t)img * NBIN;
    for (int t = tid; t < NBIN; t += 256) {
        int hk = t / 33, k = t - hk*33;
        dst[t] = scol[brev6(hk)*NWF + k];
    }
}

// ---------------- per-bin quaternion contraction: one block per bin ----------------
__global__ __launch_bounds__(256) void contract_kernel(
    const float* __restrict__ krw, const float* __restrict__ krx,
    const float* __restrict__ kry, const float* __restrict__ krz,
    const float* __restrict__ kiw, const float* __restrict__ kix,
    const float* __restrict__ kiy, const float* __restrict__ kiz,
    const float2* __restrict__ Xs, float2* __restrict__ P)
{
    const int bid = blockIdx.x;
    const int bin = (bid & 7) * (NBIN/8) + (bid >> 3);   // chunked XCD swizzle
    __shared__ float2 sW[4][32*32];    // [p][i*32+o]
    __shared__ float2 sX[4][32*32];    // [q][b*32+i]
    const int tid = threadIdx.x;

    const float* kr[4] = {krw, krx, kry, krz};
    const float* ki[4] = {kiw, kix, kiy, kiz};
    #pragma unroll
    for (int p = 0; p < 4; ++p) {
        const float* __restrict__ rr = kr[p];
        const float* __restrict__ ii = ki[p];
        for (int t = tid; t < 1024; t += 256) {
            size_t idx = (size_t)t * NBIN + bin;   // weight layout [i][o][h][wf]
            sW[p][t] = make_float2(rr[idx], ii[idx]);
        }
    }
    for (int t = tid; t < 4096; t += 256) {        // t = q*1024 + b*32 + i = img
        (&sX[0][0])[t] = Xs[(size_t)t * NBIN + bin];
    }
    __syncthreads();

    const int b  = tid >> 3;
    const int o0 = (tid & 7) << 2;
    float2 acc[4][4];
    #pragma unroll
    for (int c = 0; c < 4; ++c)
        #pragma unroll
        for (int oo = 0; oo < 4; ++oo) acc[c][oo] = make_float2(0.f, 0.f);

    for (int i = 0; i < 32; ++i) {
        float2 xw = sX[0][b*32+i], xx = sX[1][b*32+i];
        float2 xy = sX[2][b*32+i], xz = sX[3][b*32+i];
        #pragma unroll
        for (int oo = 0; oo < 4; ++oo) {
            const int o = o0 + oo;
            float2 ww = sW[0][i*32+o], wx = sW[1][i*32+o];
            float2 wy = sW[2][i*32+o], wz = sW[3][i*32+o];
            cmadd(acc[0][oo], ww, xw); cmsub(acc[0][oo], wx, xx); cmsub(acc[0][oo], wy, xy); cmsub(acc[0][oo], wz, xz);
            cmadd(acc[1][oo], ww, xx); cmadd(acc[1][oo], wx, xw); cmadd(acc[1][oo], wy, xz); cmsub(acc[1][oo], wz, xy);
            cmadd(acc[2][oo], ww, xy); cmsub(acc[2][oo], wx, xz); cmadd(acc[2][oo], wy, xw); cmadd(acc[2][oo], wz, xx);
            cmadd(acc[3][oo], ww, xz); cmadd(acc[3][oo], wx, xy); cmsub(acc[3][oo], wy, xx); cmadd(acc[3][oo], wz, xw);
        }
    }
    // P layout: [bin][p][b][o], coalesced write
    float2* __restrict__ dst = P + (size_t)bin * 4096;
    #pragma unroll
    for (int p = 0; p < 4; ++p)
        #pragma unroll
        for (int oo = 0; oo < 4; ++oo)
            dst[p*1024 + b*32 + o0 + oo] = acc[p][oo];
}

// ---------------- inverse rfft2: one block per output image ----------------
__global__ __launch_bounds__(256) void fft_inv_kernel(const float2* __restrict__ P,
                                                      float* __restrict__ out)
{
    const int bid = blockIdx.x;
    const int img = ((bid & 7) << 9) + (bid >> 3);   // chunked XCD swizzle (4096/8=512)
    const int p  = img >> 10;
    const int b  = (img >> 5) & 31;
    const int oc = img & 31;

    __shared__ float2 scol[64*NWF];    // spectra [h-freq][k] -> spatial rows (bitrev)
    __shared__ float2 zrow[32*64];     // packed complex rows for inverse row FFT
    __shared__ float2 s_tw[64];        // e^{+2pi i n/64}

    const int tid = threadIdx.x;
    if (tid < 64) {
        float ang = PI2 * (float)tid / 64.0f;
        s_tw[tid] = make_float2(cosf(ang), sinf(ang));
    }
    for (int t = tid; t < NBIN; t += 256) {
        scol[t] = P[(size_t)t * NIMG + img];   // gather from [bin][pbo]
    }
    __syncthreads();

    // inverse FFT along h (6 DIF stages, +angle twiddles); spatial h lands at brev6(h)
    for (int s = 0; s < 6; ++s) {
        const int half = 32 >> s;
        for (int t = tid; t < 1056; t += 256) {
            int j = t / 33, k = t - j*33;
            int jj = j & (half - 1);
            int p0 = ((j >> (5 - s)) << (6 - s)) + jj;
            BFLY(scol, p0*NWF + k, (p0 + half)*NWF + k, jj, s);
        }
        __syncthreads();
    }

    // build packed full spectra Z = A + iB for row pairs (2r, 2r+1)
    for (int t = tid; t < 2048; t += 256) {
        int r = t >> 6, kp = t & 63;
        int m = (kp <= 32) ? kp : 64 - kp;
        float2 A = scol[brev6(2*r)*NWF + m];
        float2 B = scol[brev6(2*r+1)*NWF + m];
        if (m == 0 || m == 32) { A.y = 0.f; B.y = 0.f; }  // irfft ignores DC/Nyq imag
        float sgn = (kp <= 32) ? 1.f : -1.f;               // Hermitian extension: conj
        A.y *= sgn; B.y *= sgn;
        zrow[r*64 + kp] = make_float2(A.x - B.y, A.y + B.x);  // Z = A + iB
    }
    __syncthreads();

    // inverse FFT along w (6 DIF stages); spatial w lands at brev6(w)
    for (int s = 0; s < 6; ++s) {
        const int half = 32 >> s;
        for (int t = tid; t < 1024; t += 256) {
            int j = t & 31, r = t >> 5;
            int jj = j & (half - 1);
            int p0 = ((j >> (5 - s)) << (6 - s)) + jj;
            float2* a = &zrow[r*64];
            BFLY(a, p0, p0 + half, jj, s);
        }
        __syncthreads();
    }

    // write out: row 2r = Re(z), row 2r+1 = Im(z), scaled by 1/4096
    const float scale = 1.0f / 4096.0f;
    float* __restrict__ dst = out + ((size_t)b*128 + (size_t)p*32 + oc) * (FH*FW);
    for (int t = tid; t < FH*FW; t += 256) {
        int row = t >> 6, w = t & 63;
        float2 z = zrow[(row >> 1)*64 + brev6(w)];
        dst[t] = ((row & 1) ? z.y : z.x) * scale;
    }
}

extern "C" void kernel_launch(void* const* d_in, const int* in_sizes, int n_in,
                              void* d_out, int out_size, void* d_ws, size_t ws_size,
                              hipStream_t stream)
{
    const float* x   = (const float*)d_in[0];
    const float* krw = (const float*)d_in[1];
    const float* krx = (const float*)d_in[2];
    const float* kry = (const float*)d_in[3];
    const float* krz = (const float*)d_in[4];
    const float* kiw = (const float*)d_in[5];
    const float* kix = (const float*)d_in[6];
    const float* kiy = (const float*)d_in[7];
    const float* kiz = (const float*)d_in[8];

    float2* Xs = (float2*)d_ws;                       // [img=4096][bin=2112]
    float2* P  = Xs + (size_t)NIMG * NBIN;            // [bin=2112][p*b*o=4096]
    float*  out = (float*)d_out;

    fft_fwd_kernel<<<dim3(NIMG), dim3(256), 0, stream>>>(x, Xs);
    contract_kernel<<<dim3(NBIN), dim3(256), 0, stream>>>(krw, krx, kry, krz,
                                                          kiw, kix, kiy, kiz, Xs, P);
    fft_inv_kernel<<<dim3(NIMG), dim3(256), 0, stream>>>(P, out);
}

// Round 3
// 201.159 us; speedup vs baseline: 3.3358x; 1.6553x over previous
//
#include <hip/hip_runtime.h>

#define FH 64
#define FW 64
#define NWF 33
#define NBIN (FH*NWF)      // 2112
#define NIMG 4096          // 4 * 32 * 32
#define PI2 6.283185307179586f

typedef unsigned short u16;
typedef __attribute__((ext_vector_type(8))) short bf16x8;
typedef __attribute__((ext_vector_type(4))) float f32x4;
typedef __attribute__((ext_vector_type(4))) int   i32x4;

__device__ __forceinline__ int brev6(int v) { return (int)(__brev((unsigned)v) >> 26); }

__device__ __forceinline__ u16 f2bf(float f) {
    unsigned u = __float_as_uint(f);
    unsigned r = (u + 0x7FFFu + ((u >> 16) & 1u)) >> 16;   // RNE
    return (u16)r;
}

// One radix-2 DIF stage butterfly.
#define BFLY(ARR, P0, P1, JJ, S)                                        \
    {                                                                   \
        float2 u = ARR[P0], v = ARR[P1];                                \
        float2 tw = s_tw[((JJ) << (S)) & 63];                           \
        float2 d = make_float2(u.x - v.x, u.y - v.y);                   \
        ARR[P0] = make_float2(u.x + v.x, u.y + v.y);                    \
        ARR[P1] = make_float2(d.x*tw.x - d.y*tw.y, d.x*tw.y + d.y*tw.x);\
    }

// ---------------- forward rfft2: one block per image ----------------
__global__ __launch_bounds__(256) void fft_fwd_kernel(const float* __restrict__ x,
                                                      float2* __restrict__ Xs)
{
    const int img = blockIdx.x;        // q*1024 + b*32 + i
    const int p  = img >> 10;
    const int b  = (img >> 5) & 31;
    const int ci = img & 31;
    const float* __restrict__ src = x + ((size_t)b*128 + (size_t)p*32 + ci) * (FH*FW);

    __shared__ float2 zrow[32*64];
    __shared__ float2 scol[64*NWF];
    __shared__ float2 s_tw[64];        // e^{-2pi i n/64}

    const int tid = threadIdx.x;
    if (tid < 64) {
        float ang = -PI2 * (float)tid / 64.0f;
        s_tw[tid] = make_float2(cosf(ang), sinf(ang));
    }
    for (int t = tid; t < 1024; t += 256) {
        float4 v = ((const float4*)src)[t];
        int flat = t << 2, row = flat >> 6, w = flat & 63;
        int r = row >> 1, comp = row & 1;
        float* base = (float*)&zrow[r*64 + w];
        base[0+comp] = v.x; base[2+comp] = v.y; base[4+comp] = v.z; base[6+comp] = v.w;
    }
    __syncthreads();

    for (int s = 0; s < 6; ++s) {
        const int half = 32 >> s;
        for (int t = tid; t < 1024; t += 256) {
            int j = t & 31, r = t >> 5;
            int jj = j & (half - 1);
            int p0 = ((j >> (5 - s)) << (6 - s)) + jj;
            float2* a = &zrow[r*64];
            BFLY(a, p0, p0 + half, jj, s);
        }
        __syncthreads();
    }

    for (int t = tid; t < 1056; t += 256) {
        int r = t / 33, k = t - r*33;
        float2 Zp = zrow[r*64 + brev6(k)];
        float2 Zq = zrow[r*64 + brev6((64 - k) & 63)];
        float2 A = make_float2(0.5f*(Zp.x + Zq.x), 0.5f*(Zp.y - Zq.y));
        float2 B = make_float2(0.5f*(Zp.y + Zq.y), -0.5f*(Zp.x - Zq.x));
        scol[(2*r)*NWF + k]   = A;
        scol[(2*r+1)*NWF + k] = B;
    }
    __syncthreads();

    for (int s = 0; s < 6; ++s) {
        const int half = 32 >> s;
        for (int t = tid; t < 1056; t += 256) {
            int j = t / 33, k = t - j*33;
            int jj = j & (half - 1);
            int p0 = ((j >> (5 - s)) << (6 - s)) + jj;
            BFLY(scol, p0*NWF + k, (p0 + half)*NWF + k, jj, s);
        }
        __syncthreads();
    }

    float2* __restrict__ dst = Xs + (size_t)img * NBIN;
    for (int t = tid; t < NBIN; t += 256) {
        int hk = t / 33, k = t - hk*33;
        dst[t] = scol[brev6(hk)*NWF + k];
    }
}

// ---------------- transpose X: [img][bin] f32 -> [bin][q][ri][b][i] bf16 ----------------
__global__ __launch_bounds__(256) void xpose_x_kernel(const float2* __restrict__ Xs,
                                                      u16* __restrict__ XT)
{
    const int g    = blockIdx.x;        // q*32 + b
    const int bin0 = blockIdx.y * 32;
    __shared__ float2 tile[32][33];
    const int tid = threadIdx.x;
    #pragma unroll
    for (int it = 0; it < 4; ++it) {
        int e = tid + it*256;
        int imgL = e >> 5, binL = e & 31;
        tile[imgL][binL] = Xs[(size_t)(g*32 + imgL) * NBIN + bin0 + binL];
    }
    __syncthreads();
    const int q = g >> 5, b = g & 31;
    #pragma unroll
    for (int it = 0; it < 4; ++it) {
        int e = tid + it*256;
        int binL = e >> 5, i = e & 31;
        float2 v = tile[i][binL];
        size_t base = ((size_t)((bin0 + binL)*4 + q)*2)*1024 + (size_t)b*32 + i;
        XT[base]        = f2bf(v.x);
        XT[base + 1024] = f2bf(v.y);
    }
}

// ---------------- transpose W: [i][o][bin] f32 -> [bin][p][ri][o][i] bf16 ----------------
__global__ __launch_bounds__(256) void prep_w_kernel(
    const float* __restrict__ s0, const float* __restrict__ s1,
    const float* __restrict__ s2, const float* __restrict__ s3,
    const float* __restrict__ s4, const float* __restrict__ s5,
    const float* __restrict__ s6, const float* __restrict__ s7,
    u16* __restrict__ WT)
{
    const int a = blockIdx.y;           // ri*4 + p  (d_in order: kr_*, ki_*)
    const int p = a & 3, ri = a >> 2;
    const float* __restrict__ src =
        (a==0)?s0:(a==1)?s1:(a==2)?s2:(a==3)?s3:(a==4)?s4:(a==5)?s5:(a==6)?s6:s7;
    const int bin0 = blockIdx.x * 16;
    __shared__ u16 lds[16][1032];       // [binL][io' = o*32+i], padded row
    const int tid = threadIdx.x;
    for (int it = 0; it < 64; ++it) {
        int e = tid + it*256;
        int io = e >> 4, binL = e & 15;
        float v = src[(size_t)io * NBIN + bin0 + binL];
        int i = io >> 5, o = io & 31;
        lds[binL][o*32 + i] = f2bf(v);
    }
    __syncthreads();
    #pragma unroll
    for (int it = 0; it < 8; ++it) {
        int c = tid + it*256;
        int binL = c >> 7, ch = c & 127;
        bf16x8 v = *(const bf16x8*)&lds[binL][ch*8];
        size_t dst = ((size_t)((bin0 + binL)*4 + p)*2 + ri)*1024 + ch*8;
        *(bf16x8*)(WT + dst) = v;
    }
}

// ---------------- per-bin quaternion contraction via MFMA ----------------
// D[b][o] = sum_i X[b][i] * W[i][o]; A-frag = X rows, B-frag = W cols.
__global__ __launch_bounds__(256) void contract_kernel(
    const u16* __restrict__ XT, const u16* __restrict__ WT,
    float2* __restrict__ P)
{
    const int bin  = blockIdx.x;
    const int wid  = threadIdx.x >> 6;
    const int lane = threadIdx.x & 63;
    const int bh = wid >> 1, oh = wid & 1;      // b-half, o-half
    const int row = lane & 15, kg = lane >> 4;  // row/col in tile, k-group

    const u16* __restrict__ xb = XT + (size_t)bin * 8192;
    const u16* __restrict__ wb = WT + (size_t)bin * 8192;

    bf16x8 ax[4][2];                            // X fragments [q][ri]
    #pragma unroll
    for (int q = 0; q < 4; ++q)
        #pragma unroll
        for (int ri = 0; ri < 2; ++ri)
            ax[q][ri] = *(const bf16x8*)(xb + ((q*2 + ri)*32 + bh*16 + row)*32 + kg*8);

    bf16x8 wpos[4][2], wneg[4][2];              // W fragments [p][ri], +/- variants
    #pragma unroll
    for (int p = 0; p < 4; ++p)
        #pragma unroll
        for (int ri = 0; ri < 2; ++ri) {
            bf16x8 w = *(const bf16x8*)(wb + ((p*2 + ri)*32 + oh*16 + row)*32 + kg*8);
            wpos[p][ri] = w;
            i32x4 t = __builtin_bit_cast(i32x4, w);
            t ^= (int)0x80008000;               // flip bf16 sign bits
            wneg[p][ri] = __builtin_bit_cast(bf16x8, t);
        }

    f32x4 acc[4][2];
    #pragma unroll
    for (int c = 0; c < 4; ++c)
        #pragma unroll
        for (int ri = 0; ri < 2; ++ri)
            acc[c][ri] = (f32x4){0.f, 0.f, 0.f, 0.f};

    // P_c = sum_q sign(c,q) * C[pi(c,q), q],  C = W (x) X complex product
    constexpr int PI_[4][4] = {{0,1,2,3},{1,0,3,2},{2,3,0,1},{3,2,1,0}};
    constexpr int SG_[4][4] = {{1,-1,-1,-1},{1,1,-1,1},{1,1,1,-1},{1,-1,1,1}};
    #pragma unroll
    for (int c = 0; c < 4; ++c)
        #pragma unroll
        for (int q = 0; q < 4; ++q) {
            const int  p   = PI_[c][q];
            const bool pos = SG_[c][q] > 0;
            bf16x8 wr_s = pos ? wpos[p][0] : wneg[p][0];   //  s*Wr
            bf16x8 wi_s = pos ? wpos[p][1] : wneg[p][1];   //  s*Wi
            bf16x8 wi_m = pos ? wneg[p][1] : wpos[p][1];   // -s*Wi
            // Re += s*(Wr*Xr - Wi*Xi) ; Im += s*(Wr*Xi + Wi*Xr)
            acc[c][0] = __builtin_amdgcn_mfma_f32_16x16x32_bf16(ax[q][0], wr_s, acc[c][0], 0, 0, 0);
            acc[c][0] = __builtin_amdgcn_mfma_f32_16x16x32_bf16(ax[q][1], wi_m, acc[c][0], 0, 0, 0);
            acc[c][1] = __builtin_amdgcn_mfma_f32_16x16x32_bf16(ax[q][1], wr_s, acc[c][1], 0, 0, 0);
            acc[c][1] = __builtin_amdgcn_mfma_f32_16x16x32_bf16(ax[q][0], wi_s, acc[c][1], 0, 0, 0);
        }

    // D layout: col(o) = lane&15, row(b) = (lane>>4)*4 + reg  ->  P[bin][c][b][o]
    float2* __restrict__ dst = P + (size_t)bin * 4096;
    #pragma unroll
    for (int c = 0; c < 4; ++c)
        #pragma unroll
        for (int r = 0; r < 4; ++r) {
            int b = bh*16 + kg*4 + r;
            int o = oh*16 + row;
            dst[c*1024 + b*32 + o] = make_float2(acc[c][0][r], acc[c][1][r]);
        }
}

// ---------------- inverse rfft2: one block per output image ----------------
__global__ __launch_bounds__(256) void fft_inv_kernel(const float2* __restrict__ P,
                                                      float* __restrict__ out)
{
    const int bid = blockIdx.x;
    const int img = ((bid & 7) << 9) + (bid >> 3);   // chunked XCD swizzle
    const int p  = img >> 10;
    const int b  = (img >> 5) & 31;
    const int oc = img & 31;

    __shared__ float2 scol[64*NWF];
    __shared__ float2 zrow[32*64];
    __shared__ float2 s_tw[64];        // e^{+2pi i n/64}

    const int tid = threadIdx.x;
    if (tid < 64) {
        float ang = PI2 * (float)tid / 64.0f;
        s_tw[tid] = make_float2(cosf(ang), sinf(ang));
    }
    for (int t = tid; t < NBIN; t += 256) {
        scol[t] = P[(size_t)t * NIMG + img];
    }
    __syncthreads();

    for (int s = 0; s < 6; ++s) {
        const int half = 32 >> s;
        for (int t = tid; t < 1056; t += 256) {
            int j = t / 33, k = t - j*33;
            int jj = j & (half - 1);
            int p0 = ((j >> (5 - s)) << (6 - s)) + jj;
            BFLY(scol, p0*NWF + k, (p0 + half)*NWF + k, jj, s);
        }
        __syncthreads();
    }

    for (int t = tid; t < 2048; t += 256) {
        int r = t >> 6, kp = t & 63;
        int m = (kp <= 32) ? kp : 64 - kp;
        float2 A = scol[brev6(2*r)*NWF + m];
        float2 B = scol[brev6(2*r+1)*NWF + m];
        if (m == 0 || m == 32) { A.y = 0.f; B.y = 0.f; }
        float sgn = (kp <= 32) ? 1.f : -1.f;
        A.y *= sgn; B.y *= sgn;
        zrow[r*64 + kp] = make_float2(A.x - B.y, A.y + B.x);
    }
    __syncthreads();

    for (int s = 0; s < 6; ++s) {
        const int half = 32 >> s;
        for (int t = tid; t < 1024; t += 256) {
            int j = t & 31, r = t >> 5;
            int jj = j & (half - 1);
            int p0 = ((j >> (5 - s)) << (6 - s)) + jj;
            float2* a = &zrow[r*64];
            BFLY(a, p0, p0 + half, jj, s);
        }
        __syncthreads();
    }

    const float scale = 1.0f / 4096.0f;
    float* __restrict__ dst = out + ((size_t)b*128 + (size_t)p*32 + oc) * (FH*FW);
    for (int t = tid; t < FH*FW; t += 256) {
        int row = t >> 6, w = t & 63;
        float2 z = zrow[(row >> 1)*64 + brev6(w)];
        dst[t] = ((row & 1) ? z.y : z.x) * scale;
    }
}

extern "C" void kernel_launch(void* const* d_in, const int* in_sizes, int n_in,
                              void* d_out, int out_size, void* d_ws, size_t ws_size,
                              hipStream_t stream)
{
    const float* x   = (const float*)d_in[0];
    const float* krw = (const float*)d_in[1];
    const float* krx = (const float*)d_in[2];
    const float* kry = (const float*)d_in[3];
    const float* krz = (const float*)d_in[4];
    const float* kiw = (const float*)d_in[5];
    const float* kix = (const float*)d_in[6];
    const float* kiy = (const float*)d_in[7];
    const float* kiz = (const float*)d_in[8];

    // Workspace: [Xs f32 / P f32 aliased: 69.2 MB][XT bf16: 34.6 MB][WT bf16: 34.6 MB]
    float2* Xs = (float2*)d_ws;
    float2* P  = (float2*)d_ws;                              // alias: Xs dead after xpose
    u16* XT = (u16*)((char*)d_ws + (size_t)NIMG*NBIN*8);
    u16* WT = XT + (size_t)NBIN*8192;
    float*  out = (float*)d_out;

    prep_w_kernel<<<dim3(NBIN/16, 8), 256, 0, stream>>>(krw, krx, kry, krz,
                                                        kiw, kix, kiy, kiz, WT);
    fft_fwd_kernel<<<dim3(NIMG), 256, 0, stream>>>(x, Xs);
    xpose_x_kernel<<<dim3(128, NBIN/32), 256, 0, stream>>>(Xs, XT);
    contract_kernel<<<dim3(NBIN), 256, 0, stream>>>(XT, WT, P);
    fft_inv_kernel<<<dim3(NIMG), 256, 0, stream>>>(P, out);
}